// Round 1
// baseline (1407.158 us; speedup 1.0000x reference)
//
#include <hip/hip_runtime.h>
#include <hip/hip_bf16.h>

// MoE top-2-of-8 FFN + shared expert + router losses, MI355X gfx950.
// Sparse (top-2) grouped bf16 MFMA GEMMs; fp32 router for exact expert selection.

#define N_TOK 8192
#define DM    1024
#define HD    4096
#define NE    8
#define NKTOT 16384            // N_TOK * 2
#define PERM_CAP 17408         // NKTOT + NE*128 (segment padding)
#define MAX_TILES 136          // sum ceil(T_e/128) <= NKTOT/128 + NE

typedef __attribute__((ext_vector_type(8))) short bhalf8;
typedef __attribute__((ext_vector_type(4))) float floatx4;

__device__ __forceinline__ unsigned short f2bf(float f) {
  union { float f; unsigned int u; } v; v.f = f;
  unsigned int u = v.u;
  return (unsigned short)((u + 0x7fffu + ((u >> 16) & 1u)) >> 16);  // RNE
}

__device__ __forceinline__ float gelu_tanh(float h) {
  // jax.nn.gelu default (approximate=True)
  float u = 0.7978845608028654f * (h + 0.044715f * h * h * h);
  float t = 1.0f - 2.0f / (1.0f + __expf(2.0f * u));   // tanh(u)
  return 0.5f * h * (1.0f + t);
}

// ---------------- init (ws is poisoned 0xAA each call) ----------------
__global__ void init_kernel(int* perm, float* permw, float* usage, float* zsum,
                            int* counts, int* fill) {
  int i = blockIdx.x * 256 + threadIdx.x;
  if (i < PERM_CAP) { perm[i] = 0; permw[i] = 0.0f; }
  if (i < NE) { usage[i] = 0.0f; counts[i] = 0; fill[i] = 0; }
  if (i == 0) zsum[0] = 0.0f;
}

// ---------------- x fp32 -> bf16 ----------------
__global__ void cvt_x_kernel(const float* __restrict__ x, unsigned short* __restrict__ xb) {
  size_t i = (size_t)(blockIdx.x * 256 + threadIdx.x) * 4;
  float4 v = *(const float4*)(x + i);
  ushort4 o;
  o.x = f2bf(v.x); o.y = f2bf(v.y); o.z = f2bf(v.z); o.w = f2bf(v.w);
  *(ushort4*)(xb + i) = o;
}

// ---------------- router: logits, top-2 softmax, aux-loss partials ----------------
__global__ void router_kernel(const float* __restrict__ x, const float* __restrict__ gw,
                              int* __restrict__ idxb, float* __restrict__ wbuf,
                              float* __restrict__ usage, float* __restrict__ zsum,
                              int* __restrict__ counts) {
  int wave = threadIdx.x >> 6;
  int lane = threadIdx.x & 63;
  int n = blockIdx.x * 4 + wave;
  const float* xr = x + (size_t)n * DM;
  float acc[NE];
#pragma unroll
  for (int e = 0; e < NE; e++) acc[e] = 0.0f;
  for (int d = lane; d < DM; d += 64) {
    float xv = xr[d];
    const float* g = gw + (size_t)d * NE;
#pragma unroll
    for (int e = 0; e < NE; e++) acc[e] += xv * g[e];
  }
#pragma unroll
  for (int e = 0; e < NE; e++) {
#pragma unroll
    for (int off = 32; off > 0; off >>= 1) acc[e] += __shfl_xor(acc[e], off);
  }
  if (lane == 0) {
    float m1 = acc[0]; int i1 = 0;
#pragma unroll
    for (int e = 1; e < NE; e++) if (acc[e] > m1) { m1 = acc[e]; i1 = e; }
    float m2 = -3.0e38f; int i2 = 0;
#pragma unroll
    for (int e = 0; e < NE; e++) if (e != i1 && acc[e] > m2) { m2 = acc[e]; i2 = e; }
    float e1 = __expf(m2 - m1);
    float w1 = 1.0f / (1.0f + e1);
    float w2 = e1 / (1.0f + e1);
    float s = 0.0f;
#pragma unroll
    for (int e = 0; e < NE; e++) s += __expf(acc[e] - m1);
    float lse = m1 + __logf(s);
    idxb[n * 2 + 0] = i1; idxb[n * 2 + 1] = i2;
    wbuf[n * 2 + 0] = w1; wbuf[n * 2 + 1] = w2;
    atomicAdd(&usage[i1], w1);
    atomicAdd(&usage[i2], w2);
    atomicAdd(zsum, lse * lse);
    atomicAdd(&counts[i1], 1);
    atomicAdd(&counts[i2], 1);
  }
}

// ---------------- scan: padded segment offsets, tile table, router loss ----------------
__global__ void scan_kernel(const int* __restrict__ counts, int* __restrict__ poff,
                            int* __restrict__ tileE, int* __restrict__ tileR,
                            int* __restrict__ nTiles,
                            const float* __restrict__ usage, const float* __restrict__ zsum,
                            float* __restrict__ lossOut) {
  if (threadIdx.x == 0 && blockIdx.x == 0) {
    int run = 0, nt = 0;
    for (int e = 0; e < NE; e++) {
      poff[e] = run;
      int t = (counts[e] + 127) >> 7;
      for (int i = 0; i < t; i++) { tileE[nt] = e; tileR[nt] = run + i * 128; nt++; }
      run += t << 7;
    }
    *nTiles = nt;
    float mean = 0.0f;
    for (int e = 0; e < NE; e++) mean += usage[e];
    mean *= (1.0f / NE);
    float var = 0.0f;
    for (int e = 0; e < NE; e++) { float d = usage[e] - mean; var += d * d; }
    var *= (1.0f / NE);
    float bal = sqrtf(var) / mean * 0.01f;
    float z = (zsum[0] / (float)N_TOK) * 0.001f;
    lossOut[0] = bal + z;
  }
}

// ---------------- scatter tokens into per-expert segments ----------------
__global__ void scatter_kernel(const int* __restrict__ idxb, const float* __restrict__ wbuf,
                               const int* __restrict__ poff, int* __restrict__ fill,
                               int* __restrict__ perm, float* __restrict__ permw) {
  int i = blockIdx.x * 256 + threadIdx.x;
  if (i < NKTOT) {
    int e = idxb[i];
    int p = poff[e] + atomicAdd(&fill[e], 1);
    perm[p] = i >> 1;
    permw[p] = wbuf[i];
  }
}

// ---------------- transpose+convert: src fp32 [R][C] -> dst bf16 [C][R], batched ----------------
__global__ void transpose_cvt_kernel(const float* __restrict__ src,
                                     unsigned short* __restrict__ dst, int R, int C) {
  __shared__ float tile[64][65];
  size_t bo = (size_t)blockIdx.z * R * C;
  src += bo; dst += bo;
  int r0 = blockIdx.x * 64, c0 = blockIdx.y * 64;
  int c = threadIdx.x & 63, r = threadIdx.x >> 6;
#pragma unroll
  for (int i = 0; i < 16; i++)
    tile[r + i * 4][c] = src[(size_t)(r0 + r + i * 4) * C + c0 + c];
  __syncthreads();
#pragma unroll
  for (int i = 0; i < 16; i++) {
    int oc = r + i * 4;           // src col -> dst row offset
    float v = tile[c][oc];        // = src[r0+c][c0+oc]
    dst[(size_t)(c0 + oc) * R + r0 + c] = f2bf(v);
  }
}

// ---------------- unified 128x128xBK64 bf16 MFMA GEMM ----------------
// MODE 0: hid = gelu(xb @ Wk_sh^T + b)            (direct rows)
// MODE 1: out = hid @ Wv_sh^T + b                 (direct rows, fp32 store)
// MODE 2: hidp = gelu(gather(xb) @ Wk_e^T + b)    (grouped, A rows via perm)
// MODE 3: out += permw * (hidp @ Wv_e^T + b)      (grouped, fp32 atomicAdd scatter)
template<int MODE>
__global__ __launch_bounds__(256) void gemm_k(
    const unsigned short* __restrict__ A,
    const unsigned short* __restrict__ BT,
    const float* __restrict__ bias,
    float* __restrict__ outF,
    unsigned short* __restrict__ outH,
    int Kd, int Nd,
    const int* __restrict__ perm,
    const float* __restrict__ permw,
    const int* __restrict__ tileE,
    const int* __restrict__ tileR,
    const int* __restrict__ nTiles) {
  __shared__ unsigned short As[128][72];   // +8 pad: frag ds_read_b128 ~2-way
  __shared__ unsigned short Bs[128][72];

  int bx = blockIdx.x;
  int n0 = blockIdx.y * 128;
  int prow0 = 0, m0 = 0;
  if (MODE >= 2) {
    if (bx >= *nTiles) return;
    int e = tileE[bx];
    prow0 = tileR[bx];
    BT += (size_t)e * Kd * Nd;
    bias += (size_t)e * Nd;
  } else {
    m0 = bx * 128;
  }

  int t = threadIdx.x;
  int c8 = (t & 7) * 8;         // k-chunk (8 bf16 = 16B)
  int rb = t >> 3;              // 0..31
  const unsigned short* aptr[4];
  const unsigned short* bptr[4];
#pragma unroll
  for (int p = 0; p < 4; p++) {
    int r = rb + p * 32;
    size_t grow;
    if (MODE == 2)      grow = (size_t)perm[prow0 + r];
    else if (MODE == 3) grow = (size_t)(prow0 + r);
    else                grow = (size_t)(m0 + r);
    aptr[p] = A + grow * Kd + c8;
    bptr[p] = BT + (size_t)(n0 + rb + p * 32) * Kd + c8;
  }

  int lane = t & 63;
  int wv = t >> 6;
  int wm = (wv >> 1) * 64, wn = (wv & 1) * 64;
  int lr = lane & 15, lq = lane >> 4;

  floatx4 acc[4][4];
#pragma unroll
  for (int i = 0; i < 4; i++)
#pragma unroll
    for (int j = 0; j < 4; j++) acc[i][j] = (floatx4){0.f, 0.f, 0.f, 0.f};

  for (int k0 = 0; k0 < Kd; k0 += 64) {
#pragma unroll
    for (int p = 0; p < 4; p++) {
      *(bhalf8*)&As[rb + p * 32][c8] = *(const bhalf8*)(aptr[p] + k0);
      *(bhalf8*)&Bs[rb + p * 32][c8] = *(const bhalf8*)(bptr[p] + k0);
    }
    __syncthreads();
#pragma unroll
    for (int kk = 0; kk < 64; kk += 32) {
      bhalf8 af[4], bf[4];
#pragma unroll
      for (int i = 0; i < 4; i++) {
        af[i] = *(const bhalf8*)&As[wm + i * 16 + lr][kk + lq * 8];
        bf[i] = *(const bhalf8*)&Bs[wn + i * 16 + lr][kk + lq * 8];
      }
#pragma unroll
      for (int mt = 0; mt < 4; mt++)
#pragma unroll
        for (int nt = 0; nt < 4; nt++)
          acc[mt][nt] = __builtin_amdgcn_mfma_f32_16x16x32_bf16(af[mt], bf[nt], acc[mt][nt], 0, 0, 0);
    }
    __syncthreads();
  }

  // epilogue: D[row=(lane>>4)*4+reg][col=lane&15]
#pragma unroll
  for (int mt = 0; mt < 4; mt++) {
#pragma unroll
    for (int nt = 0; nt < 4; nt++) {
      int ncol = n0 + wn + nt * 16 + lr;
      float bb = bias[ncol];
#pragma unroll
      for (int r = 0; r < 4; r++) {
        int mrow = wm + mt * 16 + lq * 4 + r;    // local row 0..127
        float v = acc[mt][nt][r] + bb;
        if (MODE == 0) {
          outH[(size_t)(m0 + mrow) * Nd + ncol] = f2bf(gelu_tanh(v));
        } else if (MODE == 1) {
          outF[(size_t)(m0 + mrow) * Nd + ncol] = v;
        } else if (MODE == 2) {
          outH[(size_t)(prow0 + mrow) * Nd + ncol] = f2bf(gelu_tanh(v));
        } else {
          int prow = prow0 + mrow;
          int tok = perm[prow];
          float w = permw[prow];
          atomicAdd(&outF[(size_t)tok * Nd + ncol], w * v);
        }
      }
    }
  }
}

extern "C" void kernel_launch(void* const* d_in, const int* in_sizes, int n_in,
                              void* d_out, int out_size, void* d_ws, size_t ws_size,
                              hipStream_t stream) {
  const float* x        = (const float*)d_in[0];
  const float* gate_w   = (const float*)d_in[1];
  const float* keys_w   = (const float*)d_in[2];
  const float* keys_b   = (const float*)d_in[3];
  const float* values_w = (const float*)d_in[4];
  const float* values_b = (const float*)d_in[5];
  const float* sk_w     = (const float*)d_in[6];
  const float* sk_b     = (const float*)d_in[7];
  const float* sv_w     = (const float*)d_in[8];
  const float* sv_b     = (const float*)d_in[9];
  float* out = (float*)d_out;

  char* p = (char*)d_ws;
  unsigned short* xb  = (unsigned short*)p; p += (size_t)N_TOK * DM * 2;     // 16 MB
  unsigned short* wt  = (unsigned short*)p; p += (size_t)NE * DM * HD * 2;   // 64 MB (phased)
  unsigned short* hid = (unsigned short*)p; p += (size_t)PERM_CAP * HD * 2;  // 142.6 MB
  int*   idxb   = (int*)p;   p += NKTOT * 4;
  float* wbuf   = (float*)p; p += NKTOT * 4;
  int*   perm   = (int*)p;   p += PERM_CAP * 4;
  float* permw  = (float*)p; p += PERM_CAP * 4;
  int*   counts = (int*)p;   p += NE * 4;
  int*   fill   = (int*)p;   p += NE * 4;
  int*   poff   = (int*)p;   p += NE * 4;
  float* usage  = (float*)p; p += NE * 4;
  float* zsum   = (float*)p; p += 16;
  int*   tileE  = (int*)p;   p += MAX_TILES * 4;
  int*   tileR  = (int*)p;   p += MAX_TILES * 4;
  int*   nTiles = (int*)p;   p += 16;

  float* lossOut = out + (size_t)N_TOK * DM;

  // 1) init + convert + router
  init_kernel<<<(PERM_CAP + 255) / 256, 256, 0, stream>>>(perm, permw, usage, zsum, counts, fill);
  cvt_x_kernel<<<(N_TOK * DM / 4 + 255) / 256, 256, 0, stream>>>(x, xb);
  router_kernel<<<N_TOK / 4, 256, 0, stream>>>(x, gate_w, idxb, wbuf, usage, zsum, counts);
  scan_kernel<<<1, 64, 0, stream>>>(counts, poff, tileE, tileR, nTiles, usage, zsum, lossOut);
  scatter_kernel<<<NKTOT / 256, 256, 0, stream>>>(idxb, wbuf, poff, fill, perm, permw);

  // 2) shared expert: hid = gelu(x @ Wk + b); out = hid @ Wv + b
  transpose_cvt_kernel<<<dim3(DM / 64, HD / 64, 1), 256, 0, stream>>>(sk_w, wt, DM, HD);
  gemm_k<0><<<dim3(N_TOK / 128, HD / 128), 256, 0, stream>>>(
      xb, wt, sk_b, nullptr, hid, DM, HD, perm, permw, tileE, tileR, nTiles);
  transpose_cvt_kernel<<<dim3(HD / 64, DM / 64, 1), 256, 0, stream>>>(sv_w, wt, HD, DM);
  gemm_k<1><<<dim3(N_TOK / 128, DM / 128), 256, 0, stream>>>(
      hid, wt, sv_b, out, nullptr, HD, DM, perm, permw, tileE, tileR, nTiles);

  // 3) routed experts (grouped, sparse top-2)
  transpose_cvt_kernel<<<dim3(DM / 64, HD / 64, NE), 256, 0, stream>>>(keys_w, wt, DM, HD);
  gemm_k<2><<<dim3(MAX_TILES, HD / 128), 256, 0, stream>>>(
      xb, wt, keys_b, nullptr, hid, DM, HD, perm, permw, tileE, tileR, nTiles);
  transpose_cvt_kernel<<<dim3(HD / 64, DM / 64, NE), 256, 0, stream>>>(values_w, wt, HD, DM);
  gemm_k<3><<<dim3(MAX_TILES, DM / 128), 256, 0, stream>>>(
      hid, wt, values_b, out, nullptr, HD, DM, perm, permw, tileE, tileR, nTiles);
}